// Round 7
// baseline (1823.500 us; speedup 1.0000x reference)
//
#include <hip/hip_runtime.h>
#include <hip/hip_bf16.h>

namespace {

constexpr int C = 64, H = 128, W = 128, HK = 640, WK = 640;
constexpr long long CSTR = (long long)HK * WK;   // channel stride in fkv
constexpr int PIX = 8;            // query pixels per block
constexpr int XD = 5 * PIX;       // 40 kv columns per block
constexpr int THREADS = 256;      // 4 waves

__device__ inline unsigned int packbf2(float lo, float hi) {
    __hip_bfloat162 h2 = __float22bfloat162_rn(make_float2(lo, hi));  // v_cvt_pk_bf16_f32
    return *reinterpret_cast<unsigned int*>(&h2);
}
__device__ inline float blo(unsigned int u) { return __uint_as_float(u << 16); }
__device__ inline float bhi(unsigned int u) { return __uint_as_float(u & 0xFFFF0000u); }

// ---------------- prep: Wqk = 0.125 * Wk^T Wq  (16 KB scratch) ----------------
__global__ void prep_wqk(const float* __restrict__ Wq, const float* __restrict__ Wk,
                         float* __restrict__ Wqk) {
    int tid = blockIdx.x * 256 + threadIdx.x;    // 4096 = 64*64
    int i = tid >> 6, j = tid & 63;
    float acc = 0.f;
    #pragma unroll 8
    for (int c = 0; c < 64; ++c) acc = fmaf(Wk[c * 64 + i], Wq[c * 64 + j], acc);
    Wqk[i * 64 + j] = 0.125f * acc;
}

// ---------------- fused main (R5 body + XCD swizzle), run TWICE ----------------
// ITER=2 is a DIAGNOSTIC: pass 0 writes d_out (correct result); pass 1 redoes
// identical work into d_ws, lifting dispatch dur above the ~250us harness fills
// so rocprof's top-5 finally shows this kernel's counters. Per-pass = dur/2.
__global__ __launch_bounds__(THREADS, 5)
void cag_fused(const float* __restrict__ fq, const float* __restrict__ fkv,
               const float* __restrict__ Wqk, const float* __restrict__ Wv,
               float* __restrict__ out, float* __restrict__ wsout) {
    __shared__ unsigned int slab[5 * XD * 32];       // 25600 B, bf16 pairs
    __shared__ float fq_lds[PIX * 68];               //  2176 B  [p][c]
    __shared__ float qk_lds[PIX * 68];               //  2176 B  [l][ic] f32
    __shared__ float lg[PIX * 26];                   //   832 B
    __shared__ unsigned int wsum[PIX * 36];          //  1152 B  [l][slot]

    const int t = threadIdx.x;
    // T1 bijective XCD swizzle: XCD k (= hw_bid%8) gets contiguous logical
    // range [k*1024,(k+1)*1024) = a 64-h-row band of one batch.
    const int bid = (blockIdx.x & 7) * 1024 + (blockIdx.x >> 3);
    const int wb = bid & 15;                 // W/PIX = 16
    const int h  = (bid >> 4) & 127;
    const int b  = bid >> 11;
    const int row0 = 5 * h, col0 = XD * wb, w0q = PIX * wb;

    for (int it = 0; it < 2; ++it) {
        float* outp = (it == 0) ? out : wsout;

        // ---- stage fq tile [p][c] ----
        {
            const int p = t & 7, c = t >> 3;     // c in 0..31
            fq_lds[p * 68 + c]      = fq[((size_t)(b * 64 + c) << 14) + h * 128 + w0q + p];
            fq_lds[p * 68 + c + 32] = fq[((size_t)(b * 64 + c + 32) << 14) + h * 128 + w0q + p];
        }
        // ---- stage kv slab: f32 -> packed bf16, channel-major swizzled ----
        {
            const float* kvb = fkv + (size_t)b * C * CSTR;
            for (int i = t; i < 800; i += THREADS) {     // 10 x4 * 5 y * 16 c4
                const int x4 = i % 10;
                const int y  = (i / 10) % 5;
                const int c4 = i / 50;
                const int xb = 4 * x4;
                const float* g = kvb + (size_t)(4 * c4) * CSTR
                               + (size_t)(row0 + y) * WK + (col0 + xb);
                float4 F0 = *(const float4*)(g);
                float4 F1 = *(const float4*)(g + CSTR);
                float4 F2 = *(const float4*)(g + 2 * CSTR);
                float4 F3 = *(const float4*)(g + 3 * CSTR);
                const float* f0 = (const float*)&F0; const float* f1 = (const float*)&F1;
                const float* f2 = (const float*)&F2; const float* f3 = (const float*)&F3;
                #pragma unroll
                for (int dx = 0; dx < 4; ++dx) {
                    const int x = xb + dx;
                    const int base = (y * XD + x) * 32;
                    const int sw = (((x & 7) ^ y) << 2);
                    slab[base + ((2 * c4)     ^ sw)] = packbf2(f0[dx], f1[dx]);
                    slab[base + ((2 * c4 + 1) ^ sw)] = packbf2(f2[dx], f3[dx]);
                }
            }
        }
        __syncthreads();

        // ---- qk[l][i] = sum_j Wqk[i][j] * fq_lds[l][j]  (f32) ----
        {
            const int l = t & 7, i0 = t >> 3;            // i0 in 0..31
            const float4* wr0 = (const float4*)(Wqk + i0 * 64);
            const float4* wr1 = (const float4*)(Wqk + (i0 + 32) * 64);
            const float4* fv  = (const float4*)(fq_lds + l * 68);
            float a0 = 0.f, a1 = 0.f;
            #pragma unroll
            for (int j = 0; j < 16; ++j) {
                float4 f = fv[j], w0 = wr0[j], w1 = wr1[j];
                a0 = fmaf(w0.x, f.x, a0); a0 = fmaf(w0.y, f.y, a0);
                a0 = fmaf(w0.z, f.z, a0); a0 = fmaf(w0.w, f.w, a0);
                a1 = fmaf(w1.x, f.x, a1); a1 = fmaf(w1.y, f.y, a1);
                a1 = fmaf(w1.z, f.z, a1); a1 = fmaf(w1.w, f.w, a1);
            }
            qk_lds[l * 68 + i0]      = a0;
            qk_lds[l * 68 + i0 + 32] = a1;
        }
        __syncthreads();

        // ---- logits (8x ds_read_b128) + in-wave softmax ----
        {
            const int l = t >> 5;        // pixel 0..7 (one per 32-lane group)
            const int n = t & 31;        // kv position 0..24
            float v = -1e30f;
            if (n < 25) {
                const int ky = n / 5, kx = n - 5 * (n / 5);
                const int x = 5 * l + kx;
                const int base = (ky * XD + x) * 32;
                const int sw7 = (x & 7) ^ ky;
                const float4* qv = (const float4*)(qk_lds + l * 68);
                float acc = 0.f;
                #pragma unroll
                for (int j = 0; j < 8; ++j) {
                    uint4 u = *(const uint4*)&slab[base + 4 * (j ^ sw7)];
                    float4 qa = qv[2 * j], qb = qv[2 * j + 1];
                    acc = fmaf(qa.x, blo(u.x), acc); acc = fmaf(qa.y, bhi(u.x), acc);
                    acc = fmaf(qa.z, blo(u.y), acc); acc = fmaf(qa.w, bhi(u.y), acc);
                    acc = fmaf(qb.x, blo(u.z), acc); acc = fmaf(qb.y, bhi(u.z), acc);
                    acc = fmaf(qb.z, blo(u.w), acc); acc = fmaf(qb.w, bhi(u.w), acc);
                }
                v = acc;
            }
            float m = v;
            #pragma unroll
            for (int off = 16; off; off >>= 1) m = fmaxf(m, __shfl_xor(m, off, 32));
            float e = __expf(v - m);
            float s = e;
            #pragma unroll
            for (int off = 16; off; off >>= 1) s += __shfl_xor(s, off, 32);
            if (n < 25) lg[l * 26 + n] = e / s;
        }
        __syncthreads();

        // ---- wsum[l][slot] = sum_n a[l][n] * slab[n][slot] ----
        {
            const int l = t >> 5, s = t & 31;
            float alo = 0.f, ahi = 0.f;
            #pragma unroll
            for (int n2 = 0; n2 < 25; ++n2) {
                const int ky = n2 / 5, kx = n2 - 5 * ky;         // compile-time
                const int x = 5 * l + kx;
                const unsigned int u = slab[(ky * XD + x) * 32 + (s ^ ((((x & 7) ^ ky)) << 2))];
                const float a = lg[l * 26 + n2];
                alo = fmaf(a, blo(u), alo);
                ahi = fmaf(a, bhi(u), ahi);
            }
            wsum[l * 36 + s] = packbf2(alo, ahi);
        }
        __syncthreads();

        // ---- out[oc][p] = fq[oc][p] + sum_ic Wv[oc][ic] * wsum[p][ic] ----
        {
            const int p = t & 7, o0 = t >> 3;            // o0 in 0..31
            const uint4* wsr = (const uint4*)(wsum + p * 36);
            float vals[64];
            #pragma unroll
            for (int g8 = 0; g8 < 8; ++g8) {
                uint4 u = wsr[g8];
                vals[8 * g8 + 0] = blo(u.x); vals[8 * g8 + 1] = bhi(u.x);
                vals[8 * g8 + 2] = blo(u.y); vals[8 * g8 + 3] = bhi(u.y);
                vals[8 * g8 + 4] = blo(u.z); vals[8 * g8 + 5] = bhi(u.z);
                vals[8 * g8 + 6] = blo(u.w); vals[8 * g8 + 7] = bhi(u.w);
            }
            const float4* wv0 = (const float4*)(Wv + o0 * 64);
            const float4* wv1 = (const float4*)(Wv + (o0 + 32) * 64);
            float a0 = fq_lds[p * 68 + o0];              // residual
            float a1 = fq_lds[p * 68 + o0 + 32];
            #pragma unroll
            for (int j = 0; j < 16; ++j) {
                float4 w0 = wv0[j], w1 = wv1[j];
                a0 = fmaf(w0.x, vals[4 * j + 0], a0); a0 = fmaf(w0.y, vals[4 * j + 1], a0);
                a0 = fmaf(w0.z, vals[4 * j + 2], a0); a0 = fmaf(w0.w, vals[4 * j + 3], a0);
                a1 = fmaf(w1.x, vals[4 * j + 0], a1); a1 = fmaf(w1.y, vals[4 * j + 1], a1);
                a1 = fmaf(w1.z, vals[4 * j + 2], a1); a1 = fmaf(w1.w, vals[4 * j + 3], a1);
            }
            const size_t ob = ((size_t)(b * 64 + o0) << 14) + h * 128 + w0q + p;
            outp[ob] = a0;
            outp[ob + ((size_t)32 << 14)] = a1;
        }
        __syncthreads();   // protect fq_lds/slab before next pass restages
    }
}

} // namespace

extern "C" void kernel_launch(void* const* d_in, const int* in_sizes, int n_in,
                              void* d_out, int out_size, void* d_ws, size_t ws_size,
                              hipStream_t stream) {
    (void)in_sizes; (void)n_in; (void)ws_size; (void)out_size;
    const float* fq  = (const float*)d_in[0];
    const float* fkv = (const float*)d_in[1];
    const float* Wq  = (const float*)d_in[2];
    const float* Wk  = (const float*)d_in[3];
    const float* Wv  = (const float*)d_in[4];
    float* out = (float*)d_out;
    float* Wqk = (float*)d_ws;                          // 16 KB
    float* wsout = (float*)((char*)d_ws + (1 << 20));   // diagnostic pass-2 sink (17 MB)

    prep_wqk <<<dim3(16),    dim3(256),     0, stream>>>(Wq, Wk, Wqk);
    cag_fused<<<dim3(8192),  dim3(THREADS), 0, stream>>>(fq, fkv, Wqk, Wv, out, wsout);
}

// Round 9
// 368.415 us; speedup vs baseline: 4.9496x; 4.9496x over previous
//
#include <hip/hip_runtime.h>
#include <hip/hip_bf16.h>
#include <stdint.h>

namespace {

constexpr int C = 64, H = 128, W = 128, HK = 640, WK = 640;
constexpr long long CSTR = (long long)HK * WK;   // channel stride in fkv (f32)
constexpr int PIX = 8;           // pixels per tile == waves per block
constexpr int NT = 32;           // tiles per block: 2 (b,h)-rows x 16 w-tiles
constexpr int THREADS = 512;     // 8 waves

// dynamic LDS carve (u32 units)
constexpr int OF_SLABF = 0;                    // 2 x 12800  f32 slab (dbuf, gload dest)
constexpr int OF_SLABB = 25600;                // 6400       bf16-pair slab (R5 layout)
constexpr int OF_FQ    = OF_SLABB + 6400;      // 2 x 544    fq tile [p][68]
constexpr int OF_QKW   = OF_FQ + 1088;         // 8 x 64     per-wave qk
constexpr int OF_LG    = OF_QKW + 512;         // 8 x 26     per-wave attn
constexpr int OF_WSW   = OF_LG + 208;          // 8 x 64     per-wave wsum
constexpr int SMEM_U32 = OF_WSW + 512;         // 34320 u32
constexpr int SMEM_BYTES = SMEM_U32 * 4;       // 137280 B

typedef __attribute__((address_space(1))) const void glob_void;
typedef __attribute__((address_space(3))) void lds_void;

__device__ inline unsigned int packbf2(float lo, float hi) {
    __hip_bfloat162 h2 = __float22bfloat162_rn(make_float2(lo, hi));
    return *reinterpret_cast<unsigned int*>(&h2);
}
__device__ inline float blo(unsigned int u) { return __uint_as_float(u << 16); }
__device__ inline float bhi(unsigned int u) { return __uint_as_float(u & 0xFFFF0000u); }

__device__ inline void barrier_lds() {       // drain LDS writes, sync; vmcnt stays in flight
    asm volatile("s_waitcnt lgkmcnt(0)" ::: "memory");
    __builtin_amdgcn_s_barrier();
    __builtin_amdgcn_sched_barrier(0);
}
__device__ inline void barrier_all() {       // tile boundary: drain everything
    asm volatile("s_waitcnt vmcnt(0) lgkmcnt(0)" ::: "memory");
    __builtin_amdgcn_s_barrier();
    __builtin_amdgcn_sched_barrier(0);
}

// ---------------- prep: Wqk = 0.125 * Wk^T Wq  (16 KB scratch) ----------------
__global__ void prep_wqk(const float* __restrict__ Wq, const float* __restrict__ Wk,
                         float* __restrict__ Wqk) {
    int tid = blockIdx.x * 256 + threadIdx.x;    // 4096 = 64*64
    int i = tid >> 6, j = tid & 63;
    float acc = 0.f;
    #pragma unroll 8
    for (int c = 0; c < 64; ++c) acc = fmaf(Wk[c * 64 + i], Wq[c * 64 + j], acc);
    Wqk[i * 64 + j] = 0.125f * acc;
}

// ---------------- fused main: persistent, gload_lds pipelined ----------------
__global__ __launch_bounds__(THREADS, 1)
void cag_fused(const float* __restrict__ fq, const float* __restrict__ fkv,
               const float* __restrict__ Wqk, const float* __restrict__ Wv,
               float* __restrict__ out) {
    extern __shared__ uint32_t sm[];
    uint32_t* slabf = sm + OF_SLABF;
    uint32_t* slabb = sm + OF_SLABB;
    float*    fqld  = (float*)(sm + OF_FQ);
    float*    qkw   = (float*)(sm + OF_QKW);
    float*    lg    = (float*)(sm + OF_LG);
    float*    wsw   = (float*)(sm + OF_WSW);

    const int t    = threadIdx.x;
    const int wv   = t >> 6;          // wave id == pixel within tile
    const int lane = t & 63;
    const int bid  = blockIdx.x;

    // issue 50 x global_load_lds(16B) for tile tt into f32 slab buffer d.
    // slab layout [c][y][x40] f32 linear; issue q covers u32 [q*256, q*256+256).
    auto issue_tile = [&](int tt, int d) {
        int r = (tt < 16) ? bid : bid + 256;
        int b = r >> 7, h = r & 127;
        const float* kvb = fkv + (size_t)b * C * CSTR + (size_t)(5 * h) * WK
                         + 40 * (tt & 15);
        uint32_t* dst = slabf + d * 12800;
        for (int q = wv; q < 50; q += 8) {           // uniform within wave
            int L   = q * 256 + lane * 4;            // u32 linear index
            int rr  = L / 40;                        // = c*5 + y
            int col = L - rr * 40;
            int c   = rr / 5;
            int y   = rr - c * 5;
            const float* gp = kvb + (size_t)c * CSTR + (size_t)y * WK + col;
            __builtin_amdgcn_global_load_lds((glob_void*)gp, (lds_void*)(dst + q * 256),
                                             16, 0, 0);
        }
    };

    // ---- prologue: tile 0 ----
    issue_tile(0, 0);
    {
        int b0 = bid >> 7, h0 = bid & 127;           // tile 0: wb = 0
        float v = fq[((size_t)(b0 * 64 + (t >> 3)) << 14) + h0 * 128 + (t & 7)];
        fqld[(t & 7) * 68 + (t >> 3)] = v;
    }
    barrier_all();

    for (int tile = 0; tile < NT; ++tile) {
        const int cur = tile & 1, nxt = cur ^ 1;
        const int r   = (tile < 16) ? bid : bid + 256;
        const int b   = r >> 7, h = r & 127;
        const int w0q = 8 * (tile & 15);

        // ---- issue next tile's slab + fq (loads fly under this tile's compute) ----
        float fq2 = 0.f;
        if (tile + 1 < NT) {
            issue_tile(tile + 1, nxt);
            int r2 = (tile + 1 < 16) ? bid : bid + 256;
            int b2 = r2 >> 7, h2 = r2 & 127;
            fq2 = fq[((size_t)(b2 * 64 + (t >> 3)) << 14) + h2 * 128
                     + 8 * ((tile + 1) & 15) + (t & 7)];
        }

        // ---- repack f32 slab[cur] -> bf16 swizzled slab (R5 layout) ----
        {
            const float* sf = (const float*)(slabf + cur * 12800);
            for (int i = t; i < 6400; i += THREADS) {
                int x  = i % 40;
                int y  = (i / 40) % 5;
                int cp = i / 200;                    // channel pair 0..31
                float f0 = sf[(2 * cp) * 200 + y * 40 + x];
                float f1 = sf[(2 * cp + 1) * 200 + y * 40 + x];
                slabb[(y * 40 + x) * 32 + (cp ^ ((((x & 7) ^ y)) << 2))] = packbf2(f0, f1);
            }
        }
        barrier_lds();

        // ======== per-wave chain: pixel = wv, no cross-wave deps ========
        // ---- qk: lane = channel i ----
        {
            const float4* wr = (const float4*)(Wqk + lane * 64);
            const float4* fv = (const float4*)(fqld + cur * 544 + wv * 68);
            float qv = 0.f;
            #pragma unroll
            for (int j = 0; j < 16; ++j) {
                float4 f = fv[j], wq = wr[j];
                qv = fmaf(wq.x, f.x, qv); qv = fmaf(wq.y, f.y, qv);
                qv = fmaf(wq.z, f.z, qv); qv = fmaf(wq.w, f.w, qv);
            }
            qkw[wv * 64 + lane] = qv;
        }

        // ---- logits: lane = (n 0..31) + 32*(channel-half); 4 granules each ----
        {
            const int n = lane & 31, ch = lane >> 5;
            float acc = 0.f;
            if (n < 25) {
                const int ky = n / 5, kx = n - 5 * (n / 5);
                const int x = 5 * wv + kx;
                const int base = (ky * 40 + x) * 32;
                const int sw7 = (x & 7) ^ ky;
                const float4* qg = (const float4*)(qkw + wv * 64);
                #pragma unroll
                for (int jj = 0; jj < 4; ++jj) {
                    const int j = ch * 4 + jj;
                    uint4 u = *(const uint4*)&slabb[base + 4 * (j ^ sw7)];
                    float4 qa = qg[2 * j], qb = qg[2 * j + 1];
                    acc = fmaf(qa.x, blo(u.x), acc); acc = fmaf(qa.y, bhi(u.x), acc);
                    acc = fmaf(qa.z, blo(u.y), acc); acc = fmaf(qa.w, bhi(u.y), acc);
                    acc = fmaf(qb.x, blo(u.z), acc); acc = fmaf(qb.y, bhi(u.z), acc);
                    acc = fmaf(qb.z, blo(u.w), acc); acc = fmaf(qb.w, bhi(u.w), acc);
                }
            }
            acc += __shfl_xor(acc, 32, 64);          // combine channel halves
            float v = (n < 25) ? acc : -1e30f;
            float m = v;
            #pragma unroll
            for (int off = 16; off; off >>= 1) m = fmaxf(m, __shfl_xor(m, off, 32));
            float e = __expf(v - m);
            float ssum = e;
            #pragma unroll
            for (int off = 16; off; off >>= 1) ssum += __shfl_xor(ssum, off, 32);
            if (ch == 0 && n < 25) lg[wv * 26 + n] = e / ssum;
        }

        // ---- wsum: lane = (slot s 0..31) + 32*(n-half); same-wave lg read ----
        {
            const int s = lane & 31, nh = lane >> 5;
            float alo = 0.f, ahi = 0.f;
            #define WS_STEP(n)                                                        \
                { constexpr int ky = (n) / 5, kx = (n) % 5;                           \
                  const int x = 5 * wv + kx;                                          \
                  unsigned int u = slabb[(ky * 40 + x) * 32                           \
                                         + (s ^ ((((x & 7) ^ ky)) << 2))];            \
                  float a = lg[wv * 26 + (n)];                                        \
                  alo = fmaf(a, blo(u), alo); ahi = fmaf(a, bhi(u), ahi); }
            if (nh == 0) {
                WS_STEP(0) WS_STEP(1) WS_STEP(2) WS_STEP(3) WS_STEP(4) WS_STEP(5)
                WS_STEP(6) WS_STEP(7) WS_STEP(8) WS_STEP(9) WS_STEP(10) WS_STEP(11)
                WS_STEP(12)
            } else {
                WS_STEP(13) WS_STEP(14) WS_STEP(15) WS_STEP(16) WS_STEP(17)
                WS_STEP(18) WS_STEP(19) WS_STEP(20) WS_STEP(21) WS_STEP(22)
                WS_STEP(23) WS_STEP(24)
            }
            #undef WS_STEP
            alo += __shfl_xor(alo, 32, 64);
            ahi += __shfl_xor(ahi, 32, 64);
            if (nh == 0) {
                wsw[wv * 64 + 2 * s]     = alo;      // channel 2s
                wsw[wv * 64 + 2 * s + 1] = ahi;      // channel 2s+1
            }
        }

        // ---- out: lane = oc; residual + Wv @ wsum; store ----
        {
            const float4* wvr = (const float4*)(Wv + lane * 64);
            const float4* wsr = (const float4*)(wsw + wv * 64);
            float a0 = fqld[cur * 544 + wv * 68 + lane];
            #pragma unroll
            for (int j = 0; j < 16; ++j) {
                float4 s4 = wsr[j], w4 = wvr[j];
                a0 = fmaf(w4.x, s4.x, a0); a0 = fmaf(w4.y, s4.y, a0);
                a0 = fmaf(w4.z, s4.z, a0); a0 = fmaf(w4.w, s4.w, a0);
            }
            out[((size_t)(b * 64 + lane) << 14) + h * 128 + w0q + wv] = a0;
        }

        // ---- land next tile's fq, close tile ----
        if (tile + 1 < NT) fqld[nxt * 544 + (t & 7) * 68 + (t >> 3)] = fq2;
        barrier_all();
    }
}

} // namespace

extern "C" void kernel_launch(void* const* d_in, const int* in_sizes, int n_in,
                              void* d_out, int out_size, void* d_ws, size_t ws_size,
                              hipStream_t stream) {
    (void)in_sizes; (void)n_in; (void)ws_size; (void)out_size;
    const float* fq  = (const float*)d_in[0];
    const float* fkv = (const float*)d_in[1];
    const float* Wq  = (const float*)d_in[2];
    const float* Wk  = (const float*)d_in[3];
    const float* Wv  = (const float*)d_in[4];
    float* out = (float*)d_out;
    float* Wqk = (float*)d_ws;                       // 16 KB scratch

    static_assert(SMEM_BYTES <= 160 * 1024, "LDS overflow");
    hipError_t err_ = hipFuncSetAttribute(reinterpret_cast<const void*>(&cag_fused),
                        hipFuncAttributeMaxDynamicSharedMemorySize, SMEM_BYTES);
    (void)err_;

    prep_wqk <<<dim3(16),  dim3(256),     0,          stream>>>(Wq, Wk, Wqk);
    cag_fused<<<dim3(256), dim3(THREADS), SMEM_BYTES, stream>>>(fq, fkv, Wqk, Wv, out);
}